// Round 6
// baseline (228.910 us; speedup 1.0000x reference)
//
#include <hip/hip_runtime.h>
#include <stdint.h>

#define V3 110592        // 48*48*48
#define PLANE 2304       // 48*48
#define NO 64

typedef unsigned short ushort_t;
typedef __attribute__((ext_vector_type(8))) short short8v;
typedef __attribute__((ext_vector_type(4))) float float4v;

__device__ __forceinline__ uint32_t f2bf1(float f) {
  uint32_t u = __float_as_uint(f);
  u += 0x7FFFu + ((u >> 16) & 1u);   // RNE
  return u >> 16;
}
__device__ __forceinline__ uint32_t pack2(float a, float b) {
  return f2bf1(a) | (f2bf1(b) << 16);
}

// ---------- prep: Afr[g=kk/8][m][8] bf16, kk = dzi*192 + i*6 + qi ----------
__global__ void prep_kernel(const float* __restrict__ w, ushort_t* __restrict__ Afr) {
  int idx = blockIdx.x * 256 + threadIdx.x;     // 120*64*8 = 61440
  if (idx >= 120 * 64 * 8) return;
  int r = idx & 7, m = (idx >> 3) & 63, g = idx >> 9;
  int kk = g * 8 + r;
  int dzi = kk / 192, k2 = kk % 192;
  int i = k2 / 6, qi = k2 % 6;
  const int Q[6] = {0, 1, 2, 4, 5, 8};
  const int pidx[13] = {0, 1, 2, 3, 4, 5, 6, 0, 7, 8, 0, 0, 9};  // r2 -> shell
  int dz = dzi - 2;
  int p = pidx[Q[qi] + dz * dz];
  Afr[idx] = (ushort_t)f2bf1(0.28209479177387814f * w[(m * 32 + i) * 10 + p]);
}

// ---------- pass 1: per-plane 2D class sums; NO LDS, NO barriers ----------
// wave = 6 h-rows x 52 w (lanes), 4 input channels; Bq [G=d*24+g][n][8] bf16
__global__ __launch_bounds__(256) void bq_kernel(const float* __restrict__ xb,
                                                 ushort_t* __restrict__ Bqb) {
  const int tid = threadIdx.x;
  const int lane = tid & 63;
  const int wv = tid >> 6;                       // 0..3 (6-row strips)
  const int d = blockIdx.x >> 1;                 // 0..47
  const int half = blockIdx.x & 1;
  const int ig = blockIdx.y;                     // 0..7

  const int h0 = half * 24 + wv * 6;
  const int gw = lane - 2;
  const bool okw = (gw >= 0 && gw < 48);
  const int sl1 = lane > 0 ? lane - 1 : 0;
  const int sl2 = lane > 1 ? lane - 2 : 0;
  const int sr1 = lane < 63 ? lane + 1 : 63;
  const int sr2 = lane < 62 ? lane + 2 : 63;
  const bool okst = (lane >= 2 && lane <= 49);

  const float* px[4];
#pragma unroll
  for (int ii = 0; ii < 4; ++ii)
    px[ii] = xb + ((size_t)(ig * 4 + ii) * 48 + d) * PLANE + gw;

  float a0[4][5], s1[4][5], s4[4][5];            // rolling 5-row windows

#pragma unroll
  for (int r = 0; r < 10; ++r) {
    const int gh = h0 - 2 + r;
    const bool okv = okw && (gh >= 0) && (gh < 48);
    const int slot = r % 5;
#pragma unroll
    for (int ii = 0; ii < 4; ++ii) {
      float v = okv ? px[ii][gh * 48] : 0.f;
      float vl1 = __shfl(v, sl1);
      float vr1 = __shfl(v, sr1);
      float vl2 = __shfl(v, sl2);
      float vr2 = __shfl(v, sr2);
      a0[ii][slot] = v;
      s1[ii][slot] = vl1 + vr1;
      s4[ii][slot] = vl2 + vr2;
    }
    if (r >= 4) {
      const int j0 = (r - 4) % 5, j1 = (r - 3) % 5, j2 = (r - 2) % 5,
                j3 = (r - 1) % 5, j4 = r % 5;
      uint32_t dw[12];
#pragma unroll
      for (int ii = 0; ii < 4; ++ii) {
        float B0 = a0[ii][j2];
        float B1 = s1[ii][j2] + a0[ii][j1] + a0[ii][j3];
        float B2 = s1[ii][j1] + s1[ii][j3];
        float B3 = s4[ii][j2] + a0[ii][j0] + a0[ii][j4];
        float B4 = s4[ii][j1] + s4[ii][j3] + s1[ii][j0] + s1[ii][j4];
        float B5 = s4[ii][j0] + s4[ii][j4];
        dw[ii * 3 + 0] = pack2(B0, B1);
        dw[ii * 3 + 1] = pack2(B2, B3);
        dw[ii * 3 + 2] = pack2(B4, B5);
      }
      if (okst) {
        const int n = (h0 + r - 4) * 48 + gw;
        const size_t gb = (size_t)(d * 24 + ig * 3);
        uint4 c0 = {dw[0], dw[1], dw[2], dw[3]};
        uint4 c1 = {dw[4], dw[5], dw[6], dw[7]};
        uint4 c2 = {dw[8], dw[9], dw[10], dw[11]};
        *(uint4*)(Bqb + ((gb + 0) * PLANE + n) * 8) = c0;
        *(uint4*)(Bqb + ((gb + 1) * PLANE + n) * 8) = c1;
        *(uint4*)(Bqb + ((gb + 2) * PLANE + n) * 8) = c2;
      }
    }
  }
}

// ---------- pass 2: D=2 d-blocked GEMM, linear plane walk, XCD swizzle ----------
// out[m][d0+t][n] = sum_{p,s} Afr[(p-d0-t+2)*24+s*4+quad][m] * Bq[p*24+s*4+quad][n]
#define MFMA(a, b, c) __builtin_amdgcn_mfma_f32_16x16x32_bf16(a, b, c, 0, 0, 0)
__global__ __launch_bounds__(256) void gemm_kernel(const ushort_t* __restrict__ Bq,
                                                   const ushort_t* __restrict__ Afr,
                                                   const float* __restrict__ bias,
                                                   float* __restrict__ outb) {
  const int tid = threadIdx.x;
  const int lane = tid & 63, wi = tid >> 6;
  const int quad = lane >> 4, m15 = lane & 15;

  // swizzle: intended XCD c = F&7 owns d0 in {6c, 6c+2, 6c+4}; same-XCD
  // neighbors walk d for (mostly) the same n -> plane re-reads hit its L2
  const int F = blockIdx.x;                      // 0..431
  const int c = F & 7, rr = F >> 3;              // rr 0..53
  const int dgi = rr % 3, ntile = rr / 3;        // 3 d-groups, 18 n-tiles
  const int d0 = c * 6 + dgi * 2;                // even, 0..46
  const int n0 = ntile * 128 + wi * 32;

  float4v acc[2][4][2];                          // [t][mt][nt]
#pragma unroll
  for (int t = 0; t < 2; ++t)
#pragma unroll
    for (int mt = 0; mt < 4; ++mt)
#pragma unroll
      for (int nt = 0; nt < 2; ++nt) acc[t][mt][nt] = (float4v){0.f, 0.f, 0.f, 0.f};

  const ushort_t* Bl = Bq + ((size_t)quad * PLANE + n0 + m15) * 8;
  const ushort_t* Al = Afr + ((size_t)quad * 64 + m15) * 8;

  // solo plane for t0 (dzi = 0)
  if (d0 - 2 >= 0) {
    const int p = d0 - 2;
#pragma unroll
    for (int s = 0; s < 6; ++s) {
      const ushort_t* bp = Bl + (size_t)(p * 24 + s * 4) * PLANE * 8;
      short8v b0 = *(const short8v*)(bp);
      short8v b1 = *(const short8v*)(bp + 128);
      const ushort_t* ap = Al + (size_t)(s * 4) * 64 * 8;   // dzi = 0
#pragma unroll
      for (int mt = 0; mt < 4; ++mt) {
        short8v a = *(const short8v*)(ap + mt * 128);
        acc[0][mt][0] = MFMA(a, b0, acc[0][mt][0]);
        acc[0][mt][1] = MFMA(a, b1, acc[0][mt][1]);
      }
    }
  }

  // both-t planes: p in [max(0,d0-1), min(47,d0+2)], dz_t0 = p-d0+2, dz_t1 = dz_t0-1
  const int plo = (d0 - 1 < 0) ? 0 : d0 - 1;
  const int phi = (d0 + 2 > 47) ? 47 : d0 + 2;
  for (int p = plo; p <= phi; ++p) {
    const int dz0 = p - d0 + 2;                  // 1..4
#pragma unroll
    for (int s = 0; s < 6; ++s) {
      const ushort_t* bp = Bl + (size_t)(p * 24 + s * 4) * PLANE * 8;
      short8v b0 = *(const short8v*)(bp);
      short8v b1 = *(const short8v*)(bp + 128);
      const ushort_t* ap0 = Al + (size_t)(dz0 * 24 + s * 4) * 64 * 8;
#pragma unroll
      for (int mt = 0; mt < 4; ++mt) {
        short8v a0 = *(const short8v*)(ap0 + mt * 128);
        acc[0][mt][0] = MFMA(a0, b0, acc[0][mt][0]);
        acc[0][mt][1] = MFMA(a0, b1, acc[0][mt][1]);
      }
      const ushort_t* ap1 = ap0 - (size_t)24 * 64 * 8;
#pragma unroll
      for (int mt = 0; mt < 4; ++mt) {
        short8v a1 = *(const short8v*)(ap1 + mt * 128);
        acc[1][mt][0] = MFMA(a1, b0, acc[1][mt][0]);
        acc[1][mt][1] = MFMA(a1, b1, acc[1][mt][1]);
      }
    }
  }

  // solo plane for t1 (dzi = 4)
  if (d0 + 3 <= 47) {
    const int p = d0 + 3;
#pragma unroll
    for (int s = 0; s < 6; ++s) {
      const ushort_t* bp = Bl + (size_t)(p * 24 + s * 4) * PLANE * 8;
      short8v b0 = *(const short8v*)(bp);
      short8v b1 = *(const short8v*)(bp + 128);
      const ushort_t* ap = Al + (size_t)(4 * 24 + s * 4) * 64 * 8;
#pragma unroll
      for (int mt = 0; mt < 4; ++mt) {
        short8v a = *(const short8v*)(ap + mt * 128);
        acc[1][mt][0] = MFMA(a, b0, acc[1][mt][0]);
        acc[1][mt][1] = MFMA(a, b1, acc[1][mt][1]);
      }
    }
  }

  // C/D: col(n) = lane&15, row(m) = quad*4 + reg
#pragma unroll
  for (int t = 0; t < 2; ++t) {
    const int vb = (d0 + t) * PLANE + n0 + m15;
#pragma unroll
    for (int mt = 0; mt < 4; ++mt) {
#pragma unroll
      for (int r = 0; r < 4; ++r) {
        int m = mt * 16 + quad * 4 + r;
        float bv = bias[m];
        float* op = outb + (size_t)m * V3 + vb;
#pragma unroll
        for (int nt = 0; nt < 2; ++nt)
          op[nt * 16] = acc[t][mt][nt][r] + bv;
      }
    }
  }
}
#undef MFMA

extern "C" void kernel_launch(void* const* d_in, const int* in_sizes, int n_in,
                              void* d_out, int out_size, void* d_ws, size_t ws_size,
                              hipStream_t stream) {
  const float* x    = (const float*)d_in[0];   // [2,32,1,48,48,48]
  const float* w    = (const float*)d_in[1];   // [64,32,1,1,1,10]
  const float* bias = (const float*)d_in[2];   // [64]
  float* out = (float*)d_out;                  // [2,64,1,48,48,48]

  ushort_t* Afr = (ushort_t*)d_ws;                         // 122880 B
  ushort_t* Bq  = (ushort_t*)((char*)d_ws + 131072);       // 42.5 MB

  prep_kernel<<<240, 256, 0, stream>>>(w, Afr);
  for (int b = 0; b < 2; ++b) {
    bq_kernel<<<dim3(96, 8), 256, 0, stream>>>(x + (size_t)b * 32 * V3, Bq);
    gemm_kernel<<<432, 256, 0, stream>>>(Bq, Afr, bias, out + (size_t)b * NO * V3);
  }
}